// Round 8
// baseline (455.157 us; speedup 1.0000x reference)
//
#include <hip/hip_runtime.h>

#define N_ROWS  65536
#define D       1024
#define NB      512              // 2 blocks/CU, 8 waves/CU
#define TPB     256
#define RPT     (N_ROWS / NB)    // 128 rows/thread, compile-time
#define K_NEIGH 64
#define NACC    8                // accumulator replicas: 512 -> 64 atomics/address

// Fused: per-column sum-of-squared-diffs (streaming, HBM-bound) + last-block
// top-k. Thread t owns 4 consecutive columns (one float4); a block's 256
// threads cover one full 1024-float row per step (wave reads 1 KiB
// contiguous). Block b handles rows b, b+NB, ...
__global__ __launch_bounds__(TPB) void lm_fused(
    const int* __restrict__ gid,
    const float* __restrict__ x,
    float* __restrict__ ws,      // [NACC][D] acc replicas + [1] uint counter
    float* __restrict__ out)
{
    const int t   = threadIdx.x;
    const int col = t << 2;
    const int g   = gid[0];

    const float4 sel = *reinterpret_cast<const float4*>(x + (size_t)g * D + col);

    float a0 = 0.f, a1 = 0.f, a2 = 0.f, a3 = 0.f;
    const float* p = x + (size_t)blockIdx.x * D + col;

    #pragma unroll 8
    for (int i = 0; i < RPT; ++i) {
        float4 v = *reinterpret_cast<const float4*>(p);
        p += (size_t)NB * D;
        float d0 = sel.x - v.x;
        float d1 = sel.y - v.y;
        float d2 = sel.z - v.z;
        float d3 = sel.w - v.w;
        a0 = fmaf(d0, d0, a0);
        a1 = fmaf(d1, d1, a1);
        a2 = fmaf(d2, d2, a2);
        a3 = fmaf(d3, d3, a3);
    }

    // replica (blockIdx & 7): 64 serialized adds per address instead of 512
    float* acc = ws + (size_t)(blockIdx.x & (NACC - 1)) * D;
    atomicAdd(&acc[col + 0], a0);
    atomicAdd(&acc[col + 1], a1);
    atomicAdd(&acc[col + 2], a2);
    atomicAdd(&acc[col + 3], a3);

    // ---- last-block detection (release our adds, then count) ----
    __shared__ int is_last;
    __threadfence();                         // adds visible before counter bump
    if (t == 0) {
        unsigned* cnt = (unsigned*)(ws + NACC * D);
        unsigned old = atomicAdd(cnt, 1u);
        is_last = (old == NB - 1);
    }
    __syncthreads();
    if (!is_last) return;

    // ---- last block: gather replicas (agent-scope loads: fresh values from
    // the device coherence point regardless of XCD), then bitonic top-k ----
    __threadfence();                         // acquire side
    __shared__ float s[D];
    for (int c = t; c < D; c += TPB) {
        float v = 0.f;
        #pragma unroll
        for (int r = 0; r < NACC; ++r)
            v += __hip_atomic_load(&ws[(size_t)r * D + c],
                                   __ATOMIC_RELAXED, __HIP_MEMORY_SCOPE_AGENT);
        s[c] = v;
    }
    __syncthreads();

    // bitonic sort ascending: 256 threads x 4 elements (pairs disjoint per
    // stage; only the lower index of each pair swaps)
    for (int k = 2; k <= D; k <<= 1) {
        for (int j = k >> 1; j > 0; j >>= 1) {
            for (int dd = t; dd < D; dd += TPB) {
                int ixj = dd ^ j;
                if (ixj > dd) {
                    float a = s[dd], b = s[ixj];
                    bool asc = ((dd & k) == 0);
                    if ((a > b) == asc) { s[dd] = b; s[ixj] = a; }
                }
            }
            __syncthreads();
        }
    }

    if (t < K_NEIGH) {                       // threads 0..63 = one wave
        float v = sqrtf(s[t]);
        #pragma unroll
        for (int off = 32; off > 0; off >>= 1) v += __shfl_down(v, off);
        if (t == 0) out[0] = v * (1.0f / K_NEIGH);
    }
}

extern "C" void kernel_launch(void* const* d_in, const int* in_sizes, int n_in,
                              void* d_out, int out_size, void* d_ws, size_t ws_size,
                              hipStream_t stream)
{
    const int*   gid = (const int*)d_in[0];    // group_id (scalar int)
    const float* x   = (const float*)d_in[1];  // all_latents [N_ROWS*D] fp32
    float*       out = (float*)d_out;          // scalar fp32
    float*       ws  = (float*)d_ws;           // NACC*D floats + counter

    // d_ws is re-poisoned to 0xAA each replay: zero replicas + counter
    hipMemsetAsync(ws, 0, (NACC * D) * sizeof(float) + sizeof(unsigned), stream);

    lm_fused<<<NB, TPB, 0, stream>>>(gid, x, ws, out);
}